// Round 29
// baseline (81.702 us; speedup 1.0000x reference)
//
#include <hip/hip_runtime.h>

namespace {
constexpr int kNP = 8, kNR = 12;
constexpr int kRelCell = 288;          // NP*K*NR floats per cell (1152 B)
constexpr int kH = 64, kNOUT = 64;
constexpr int CELLS = 2;               // cells per wave
constexpr int WAVES = 8;               // 512-thread blocks
constexpr int WT2_LD = 130;            // padded d-pair row: 2-way aliases only
}

typedef float v2f __attribute__((ext_vector_type(2)));

__device__ __forceinline__ float readlane_f(float v, int l) {
    union { float f; int i; } u; u.f = v;
    u.i = __builtin_amdgcn_readlane(u.i, l);
    return u.f;
}

// DPP add step on the VALU pipe; invalid source lanes contribute 0.
template<int CTRL>
__device__ __forceinline__ float dpp_add(float x) {
    int y = __builtin_amdgcn_update_dpp(0, __float_as_int(x), CTRL, 0xf, 0xf, true);
    return x + __int_as_float(y);
}
// 64-lane sum (no DS ops); lane 63 holds the total.
__device__ __forceinline__ float wave_sum63(float x) {
    x = dpp_add<0x111>(x);  // row_shr:1
    x = dpp_add<0x112>(x);  // row_shr:2
    x = dpp_add<0x114>(x);  // row_shr:4
    x = dpp_add<0x118>(x);  // row_shr:8
    x = dpp_add<0x142>(x);  // row_bcast:15
    x = dpp_add<0x143>(x);  // row_bcast:31
    return x;
}

// L2-warming prefetch of one 288-float cell (scalar-path blocks only).
__device__ __forceinline__ void pf_issue(const float* cb, int lane,
                                         float4* a, float* b) {
    *a = *(const float4*)(cb + lane * 4);
    *b = cb[224 + lane];
}
#define PF_SINK(a, b) asm volatile("" :: "v"((a).x), "v"((a).y), "v"((a).z), "v"((a).w), "v"(b))

// async global->LDS, 16 B/lane; LDS dest = uniform base + lane*16 (exec-masked)
__device__ __forceinline__ void gll16(const float* g, float* l) {
    __builtin_amdgcn_global_load_lds(
        (const __attribute__((address_space(1))) void*)g,
        (__attribute__((address_space(3))) void*)l, 16, 0, 0);
}
// stage one 288-float cell: 1024 B (all lanes) + 128 B (lanes 0-7) [r19-verified]
__device__ __forceinline__ void stage_cell(const float* g, float* lds, int lane) {
    gll16(g + lane * 4, lds);
    if (lane < 8) gll16(g + 256 + lane * 4, lds + 256);
}

// SCALAR-path cell (r24-verified form): wave-uniform global pointer -> s_load
// batches; packed v_pk_fma_f32 dots. STRUCTURALLY DISTINCT from cell_z_lds
// (v2f/pk vs float4/scalar-fma) so the compiler cannot tail-merge the two
// branch bodies into a generic-pointer PHI (the r27/r28 failure mode).
__device__ __forceinline__ float cell_z(const float* __restrict__ cb,
                                        const v2f* __restrict__ dreg2,
                                        float sv_i, float wz2) {
    float zj[kNP], la[kNP];
#pragma unroll
    for (int p = 0; p < kNP; ++p) {
        const v2f* r2 = (const v2f*)(cb + p * 36);
        v2f a0 = {0.f, 0.f}, a1 = {0.f, 0.f}, a2 = {0.f, 0.f};
#pragma unroll
        for (int rr = 0; rr < 6; ++rr) {
            a0 = __builtin_elementwise_fma(r2[rr],      dreg2[rr], a0);
            a1 = __builtin_elementwise_fma(r2[6 + rr],  dreg2[rr], a1);
            a2 = __builtin_elementwise_fma(r2[12 + rr], dreg2[rr], a2);
        }
        const float d0 = a0.x + a0.y;
        const float d1 = a1.x + a1.y;
        const float d2 = a2.x + a2.y;
        const float z = d0 * d1 * d2 * sv_i;
        zj[p] = z;
        la[p] = z * wz2;
    }
#pragma unroll
    for (int p = 0; p < kNP; ++p) la[p] = wave_sum63(la[p]);
    float esum = 0.f, zd = 0.f;
#pragma unroll
    for (int p = 0; p < kNP; ++p) {
        const float e = __builtin_amdgcn_exp2f(readlane_f(la[p], 63));
        esum += e;
        zd = fmaf(e, zj[p], zd);
    }
    return zd * __builtin_amdgcn_rcpf(esum);
}

// LDS-path cell (r19-verified form): LDS pointer -> broadcast ds_read_b128;
// float4 loads + scalar fmaf chains. Different instruction mix from cell_z
// by design (anti-merge).
__device__ __forceinline__ float cell_z_lds(const float* cb,
                                            const v2f* __restrict__ dreg2,
                                            float sv_i, float wz2) {
    float zj[kNP], la[kNP];
#pragma unroll
    for (int p = 0; p < kNP; ++p) {
        const float4* r4 = (const float4*)(cb + p * 36);
        const float4 a0 = r4[0], a1 = r4[1], a2 = r4[2];
        const float4 b0 = r4[3], b1 = r4[4], b2 = r4[5];
        const float4 c0 = r4[6], c1 = r4[7], c2 = r4[8];
        float d0 = a0.x*dreg2[0].x + a0.y*dreg2[0].y + a0.z*dreg2[1].x + a0.w*dreg2[1].y
                 + a1.x*dreg2[2].x + a1.y*dreg2[2].y + a1.z*dreg2[3].x + a1.w*dreg2[3].y
                 + a2.x*dreg2[4].x + a2.y*dreg2[4].y + a2.z*dreg2[5].x + a2.w*dreg2[5].y;
        float d1 = b0.x*dreg2[0].x + b0.y*dreg2[0].y + b0.z*dreg2[1].x + b0.w*dreg2[1].y
                 + b1.x*dreg2[2].x + b1.y*dreg2[2].y + b1.z*dreg2[3].x + b1.w*dreg2[3].y
                 + b2.x*dreg2[4].x + b2.y*dreg2[4].y + b2.z*dreg2[5].x + b2.w*dreg2[5].y;
        float d2 = c0.x*dreg2[0].x + c0.y*dreg2[0].y + c0.z*dreg2[1].x + c0.w*dreg2[1].y
                 + c1.x*dreg2[2].x + c1.y*dreg2[2].y + c1.z*dreg2[3].x + c1.w*dreg2[3].y
                 + c2.x*dreg2[4].x + c2.y*dreg2[4].y + c2.z*dreg2[5].x + c2.w*dreg2[5].y;
        const float z = d0 * d1 * d2 * sv_i;
        zj[p] = z;
        la[p] = z * wz2;
    }
#pragma unroll
    for (int p = 0; p < kNP; ++p) la[p] = wave_sum63(la[p]);
    float esum = 0.f, zd = 0.f;
#pragma unroll
    for (int p = 0; p < kNP; ++p) {
        const float e = __builtin_amdgcn_exp2f(readlane_f(la[p], 63));
        esum += e;
        zd = fmaf(e, zj[p], zd);
    }
    return zd * __builtin_amdgcn_rcpf(esum);
}

// grid: 128 (b,v) x 16 f = 2048 blocks of 512 threads (8 waves); wave w ->
// t = 2w..2w+1 (r24 champion geometry). Resource split by ROUND PARITY
// ((blockIdx>>8)&1): even rounds consume rel via the scalar K$ port, odd
// rounds via global_load_lds + broadcast ds_read. Under RR dispatch each CU
// hosts both parities concurrently -> the two ~1.4 B/cyc/CU broadcast ports
// each carry half the stream and overlap. Anti-merge: structurally distinct
// cell_z / cell_z_lds bodies (r27/r28 collapsed via tail-merge -> flat loads).
__global__ __launch_bounds__(512, 4) void gal_kernel(
    const float* __restrict__ rel,      // (BS,NV,MF,MT,NP,K,NR)
    const float* __restrict__ se,       // (BS,NV,MT,MF,H)
    const float* __restrict__ s,        // unused (cancels in softmax)
    const float* __restrict__ Wstack,   // (NR,H,H)
    const float* __restrict__ lin_w,    // (1,H+NOUT)
    const float* __restrict__ lin_b,    // unused (cancels)
    const float* __restrict__ out_w,    // (NOUT,H)
    const float* __restrict__ out_b,    // (NOUT,)
    float* __restrict__ out)            // (BS,NV,NOUT)
{
    __shared__ __align__(16) float wT2[32 * WT2_LD];                // 16.6 KB (d-pair)
    __shared__ __align__(16) float relbuf[WAVES][CELLS][kRelCell];  // 18 KB (LDS rounds)
    __shared__ __align__(16) float dshare[kNR * kH];                // 3 KB diag; reused as redbuf

    const int tid  = (int)threadIdx.x;
    const int lane = tid & 63;
    const int w    = __builtin_amdgcn_readfirstlane(tid >> 6);  // uniform wave id 0..7

    const int bid = __builtin_amdgcn_readfirstlane((int)blockIdx.x);
    const int bv  = bid >> 4;              // 0..127
    const int f   = bid & 15;
    const int t0  = w * CELLS;
    const bool lds_path = ((bid >> 8) & 1) != 0;   // round parity: mixes per CU

    const float* relbase = rel + ((size_t)((bv * 16 + f) * 16) + t0) * kRelCell;

    // branch-local rel acquisition (block-uniform branch, s_cbranch)
    float4 pfa0, pfa1; float pfb0, pfb1;
    if (lds_path) {
        stage_cell(relbase,            &relbuf[w][0][0], lane);
        stage_cell(relbase + kRelCell, &relbuf[w][1][0], lane);
    } else {
        pf_issue(relbase,            lane, &pfa0, &pfb0);
        pf_issue(relbase + kRelCell, lane, &pfa1, &pfb1);
    }

    // out_w (o,d) -> wT2[(d>>1)*130 + o*2 + (d&1)]: coalesced global read;
    // LDS writes 2-way bank-aliased (free per m136)
    for (int i = tid; i < kH * kNOUT; i += 512) {
        const int o = i >> 6, d = i & 63;
        wT2[(d >> 1) * WT2_LD + o * 2 + (d & 1)] = out_w[i];
    }
    // diag gather (stride-65 in Wstack) once per block
    for (int i = tid; i < kNR * kH; i += 512) {
        const int r = i >> 6, d = i & 63;
        dshare[i] = Wstack[r * kH * kH + d * (kH + 1)];
    }

    const float wz2 = lin_w[kNOUT + lane] * 1.44269504088896340736f;  // log2(e)
    const float ob = out_b[lane];   // lane = o in epilogue
    const float* sep = se + ((size_t)(bv * 16 + t0) * 16 + f) * kH + lane;
    float sev[CELLS];
#pragma unroll
    for (int i = 0; i < CELLS; ++i) sev[i] = sep[(size_t)i * (16 * kH)];

    __syncthreads();                 // B1: wT2 + dshare + (lds rounds) staging landed
    v2f dreg2[6];
#pragma unroll
    for (int rr = 0; rr < 6; ++rr) {
        dreg2[rr].x = dshare[(2 * rr) * kH + lane];      // stride-1: conflict-free
        dreg2[rr].y = dshare[(2 * rr + 1) * kH + lane];
    }
    __syncthreads();                 // B2: diag consumed -> dshare free for redbuf

    float zreg[CELLS];
    if (lds_path) {
        __builtin_amdgcn_sched_barrier(0);
        zreg[0] = cell_z_lds(&relbuf[w][0][0], dreg2, sev[0], wz2);  // ds_read stream
        zreg[1] = cell_z_lds(&relbuf[w][1][0], dreg2, sev[1], wz2);
        __builtin_amdgcn_sched_barrier(0);
    } else {
        zreg[0] = cell_z(relbase,            dreg2, sev[0], wz2);    // s_load stream
        PF_SINK(pfa0, pfb0);
        zreg[1] = cell_z(relbase + kRelCell, dreg2, sev[1], wz2);
        PF_SINK(pfa1, pfb1);
    }

    // epilogue: d-pair packed 64x64 matvec over 2 cells; lane = o
    v2f Q0 = {0.f, 0.f}, Q1 = {0.f, 0.f};
#pragma unroll
    for (int d2 = 0; d2 < 32; ++d2) {
        const v2f wv = *(const v2f*)&wT2[d2 * WT2_LD + lane * 2];  // b64, 2-way alias
        v2f zz0, zz1;
        zz0.x = readlane_f(zreg[0], 2 * d2);
        zz0.y = readlane_f(zreg[0], 2 * d2 + 1);
        zz1.x = readlane_f(zreg[1], 2 * d2);
        zz1.y = readlane_f(zreg[1], 2 * d2 + 1);
        Q0 = __builtin_elementwise_fma(wv, zz0, Q0);
        Q1 = __builtin_elementwise_fma(wv, zz1, Q1);
    }
    const float q0 = Q0.x + Q0.y, q1 = Q1.x + Q1.y;
    const float tot = fmaxf(q0 + ob, 0.f) + fmaxf(q1 + ob, 0.f);

    // block reduce (dshare[0..511] reused) -> one wave-atomic per block
    dshare[w * 64 + lane] = tot;
    __syncthreads();                 // B3
    if (w == 0) {
        float r = 0.f;
#pragma unroll
        for (int j = 0; j < WAVES; ++j) r += dshare[j * 64 + lane];
        atomicAdd(&out[bv * kNOUT + lane], r);
    }
}

extern "C" void kernel_launch(void* const* d_in, const int* in_sizes, int n_in,
                              void* d_out, int out_size, void* d_ws, size_t ws_size,
                              hipStream_t stream) {
    const float* rel   = (const float*)d_in[0];
    const float* sem   = (const float*)d_in[1];
    const float* s     = (const float*)d_in[2];
    const float* Wst   = (const float*)d_in[3];
    const float* lin_w = (const float*)d_in[4];
    const float* lin_b = (const float*)d_in[5];
    const float* out_w = (const float*)d_in[6];
    const float* out_b = (const float*)d_in[7];
    float* out = (float*)d_out;

    hipMemsetAsync(out, 0, sizeof(float) * 8 * 16 * kNOUT, stream);
    dim3 grid(2048), block(512);
    hipLaunchKernelGGL(gal_kernel, grid, block, 0, stream,
                       rel, sem, s, Wst, lin_w, lin_b, out_w, out_b, out);
}

// Round 30
// 42.496 us; speedup vs baseline: 1.9226x; 1.9226x over previous
//
#include <hip/hip_runtime.h>

namespace {
constexpr int kNP = 8, kNR = 12;
constexpr int kRelCell = 288;          // NP*K*NR floats per cell (1152 B)
constexpr int kH = 64, kNOUT = 64;
constexpr int CELLS = 2;               // cells per wave
constexpr int WAVES = 8;               // 512-thread blocks
constexpr int WT2_LD = 130;            // padded d-pair row: 2-way aliases only
}

typedef float v2f __attribute__((ext_vector_type(2)));

__device__ __forceinline__ float readlane_f(float v, int l) {
    union { float f; int i; } u; u.f = v;
    u.i = __builtin_amdgcn_readlane(u.i, l);
    return u.f;
}

// DPP add step on the VALU pipe; invalid source lanes contribute 0.
template<int CTRL>
__device__ __forceinline__ float dpp_add(float x) {
    int y = __builtin_amdgcn_update_dpp(0, __float_as_int(x), CTRL, 0xf, 0xf, true);
    return x + __int_as_float(y);
}
// 64-lane sum (no DS ops); lane 63 holds the total.
__device__ __forceinline__ float wave_sum63(float x) {
    x = dpp_add<0x111>(x);  // row_shr:1
    x = dpp_add<0x112>(x);  // row_shr:2
    x = dpp_add<0x114>(x);  // row_shr:4
    x = dpp_add<0x118>(x);  // row_shr:8
    x = dpp_add<0x142>(x);  // row_bcast:15
    x = dpp_add<0x143>(x);  // row_bcast:31
    return x;
}

// L2-warming prefetch of one 288-float cell: float4 covers floats 0..255,
// dword covers 224..287 -- complete, no OOB past the cell.
__device__ __forceinline__ void pf_issue(const float* cb, int lane,
                                         float4* a, float* b) {
    *a = *(const float4*)(cb + lane * 4);
    *b = cb[224 + lane];
}
// keep prefetch registers alive (placed AFTER the compute: waitcnt satisfied)
#define PF_SINK(a, b) asm volatile("" :: "v"((a).x), "v"((a).y), "v"((a).z), "v"((a).w), "v"(b))

// One cell's logits+softmax+combine; cb is wave-uniform -> scalar s_load path
// (packed v_pk_fma_f32 dots, r22/r24 champion). wz2 pre-scaled by log2(e);
// raw v_exp_f32, no max subtraction (logits bounded far below exp2's 127),
// v_rcp vs precise divide (1 ulp, thr 0.2%).
__device__ __forceinline__ float cell_z(const float* __restrict__ cb,
                                        const v2f* __restrict__ dreg2,
                                        float sv_i, float wz2) {
    float zj[kNP], la[kNP];
#pragma unroll
    for (int p = 0; p < kNP; ++p) {
        const v2f* r2 = (const v2f*)(cb + p * 36);   // 18 wave-uniform float2
        v2f a0 = {0.f, 0.f}, a1 = {0.f, 0.f}, a2 = {0.f, 0.f};
#pragma unroll
        for (int rr = 0; rr < 6; ++rr) {
            a0 = __builtin_elementwise_fma(r2[rr],      dreg2[rr], a0);
            a1 = __builtin_elementwise_fma(r2[6 + rr],  dreg2[rr], a1);
            a2 = __builtin_elementwise_fma(r2[12 + rr], dreg2[rr], a2);
        }
        const float d0 = a0.x + a0.y;
        const float d1 = a1.x + a1.y;
        const float d2 = a2.x + a2.y;
        const float z = d0 * d1 * d2 * sv_i;
        zj[p] = z;
        la[p] = z * wz2;
    }
#pragma unroll
    for (int p = 0; p < kNP; ++p) la[p] = wave_sum63(la[p]);
    float esum = 0.f, zd = 0.f;
#pragma unroll
    for (int p = 0; p < kNP; ++p) {
        const float e = __builtin_amdgcn_exp2f(readlane_f(la[p], 63));
        esum += e;
        zd = fmaf(e, zj[p], zd);
    }
    return zd * __builtin_amdgcn_rcpf(esum);
}

// grid: 128 (b,v) x 16 f = 2048 blocks of 512 threads (8 waves); wave w ->
// t = 2w..2w+1 (r24 champion geometry/path). ONLY change vs r24: separate
// 2 KB redbuf so barrier B2 is gone -- waves enter the scalar-stall region
// un-resynchronized (B1..cell-loop had a block rendezvous right before the
// K$-fill chains; staggered entry spreads the per-CU fill slots in time).
__global__ __launch_bounds__(512, 4) void gal_kernel(
    const float* __restrict__ rel,      // (BS,NV,MF,MT,NP,K,NR)
    const float* __restrict__ se,       // (BS,NV,MT,MF,H)
    const float* __restrict__ s,        // unused (cancels in softmax)
    const float* __restrict__ Wstack,   // (NR,H,H)
    const float* __restrict__ lin_w,    // (1,H+NOUT)
    const float* __restrict__ lin_b,    // unused (cancels)
    const float* __restrict__ out_w,    // (NOUT,H)
    const float* __restrict__ out_b,    // (NOUT,)
    float* __restrict__ out)            // (BS,NV,NOUT)
{
    __shared__ __align__(16) float wT2[32 * WT2_LD];   // 16.6 KB (d-pair layout)
    __shared__ __align__(16) float dshare[kNR * kH];   // 3 KB diag (read-only after B1)
    __shared__ __align__(16) float redbuf[WAVES * 64]; // 2 KB

    const int tid  = (int)threadIdx.x;
    const int lane = tid & 63;
    const int w    = __builtin_amdgcn_readfirstlane(tid >> 6);  // uniform wave id 0..7

    const int bv = (int)blockIdx.x >> 4;   // 0..127
    const int f  = (int)blockIdx.x & 15;
    const int t0 = w * CELLS;

    const float* relbase = rel + ((size_t)((bv * 16 + f) * 16) + t0) * kRelCell;

    // prefetch both cells immediately (warm L2 for the scalar loads)
    float4 pfa0, pfa1; float pfb0, pfb1;
    pf_issue(relbase,            lane, &pfa0, &pfb0);
    pf_issue(relbase + kRelCell, lane, &pfa1, &pfb1);

    // out_w (o,d) -> wT2[(d>>1)*130 + o*2 + (d&1)]: coalesced global read;
    // LDS writes 2-way bank-aliased (free per m136)
    for (int i = tid; i < kH * kNOUT; i += 512) {
        const int o = i >> 6, d = i & 63;
        wT2[(d >> 1) * WT2_LD + o * 2 + (d & 1)] = out_w[i];
    }
    // diag gather (stride-65 in Wstack) once per block
    for (int i = tid; i < kNR * kH; i += 512) {
        const int r = i >> 6, d = i & 63;
        dshare[i] = Wstack[r * kH * kH + d * (kH + 1)];
    }

    const float wz2 = lin_w[kNOUT + lane] * 1.44269504088896340736f;  // log2(e)
    const float ob = out_b[lane];   // lane = o in epilogue
    const float* sep = se + ((size_t)(bv * 16 + t0) * 16 + f) * kH + lane;
    float sev[CELLS];
#pragma unroll
    for (int i = 0; i < CELLS; ++i) sev[i] = sep[(size_t)i * (16 * kH)];

    __syncthreads();                 // B1: wT2 + dshare staged (+ prefetch drained)
    v2f dreg2[6];
#pragma unroll
    for (int rr = 0; rr < 6; ++rr) {
        dreg2[rr].x = dshare[(2 * rr) * kH + lane];      // stride-1: conflict-free
        dreg2[rr].y = dshare[(2 * rr + 1) * kH + lane];
    }
    // no B2: dshare is read-only from here; redbuf is a separate buffer.
    // Waves enter the scalar-chain region staggered.

    float zreg[CELLS];
    zreg[0] = cell_z(relbase,            dreg2, sev[0], wz2);
    PF_SINK(pfa0, pfb0);
    zreg[1] = cell_z(relbase + kRelCell, dreg2, sev[1], wz2);
    PF_SINK(pfa1, pfb1);

    // epilogue: d-pair packed 64x64 matvec over 2 cells; lane = o
    v2f Q0 = {0.f, 0.f}, Q1 = {0.f, 0.f};
#pragma unroll
    for (int d2 = 0; d2 < 32; ++d2) {
        const v2f wv = *(const v2f*)&wT2[d2 * WT2_LD + lane * 2];  // b64, 2-way alias
        v2f zz0, zz1;
        zz0.x = readlane_f(zreg[0], 2 * d2);
        zz0.y = readlane_f(zreg[0], 2 * d2 + 1);
        zz1.x = readlane_f(zreg[1], 2 * d2);
        zz1.y = readlane_f(zreg[1], 2 * d2 + 1);
        Q0 = __builtin_elementwise_fma(wv, zz0, Q0);
        Q1 = __builtin_elementwise_fma(wv, zz1, Q1);
    }
    const float q0 = Q0.x + Q0.y, q1 = Q1.x + Q1.y;
    const float tot = fmaxf(q0 + ob, 0.f) + fmaxf(q1 + ob, 0.f);

    // block reduce -> one wave-atomic per block
    redbuf[w * 64 + lane] = tot;
    __syncthreads();                 // B3
    if (w == 0) {
        float r = 0.f;
#pragma unroll
        for (int j = 0; j < WAVES; ++j) r += redbuf[j * 64 + lane];
        atomicAdd(&out[bv * kNOUT + lane], r);
    }
}

extern "C" void kernel_launch(void* const* d_in, const int* in_sizes, int n_in,
                              void* d_out, int out_size, void* d_ws, size_t ws_size,
                              hipStream_t stream) {
    const float* rel   = (const float*)d_in[0];
    const float* sem   = (const float*)d_in[1];
    const float* s     = (const float*)d_in[2];
    const float* Wst   = (const float*)d_in[3];
    const float* lin_w = (const float*)d_in[4];
    const float* lin_b = (const float*)d_in[5];
    const float* out_w = (const float*)d_in[6];
    const float* out_b = (const float*)d_in[7];
    float* out = (float*)d_out;

    hipMemsetAsync(out, 0, sizeof(float) * 8 * 16 * kNOUT, stream);
    dim3 grid(2048), block(512);
    hipLaunchKernelGGL(gal_kernel, grid, block, 0, stream,
                       rel, sem, s, Wst, lin_w, lin_b, out_w, out_b, out);
}